// Round 12
// baseline (170.269 us; speedup 1.0000x reference)
//
#include <hip/hip_runtime.h>
#include <hip/hip_bf16.h>

#define C_DIM 512
#define H_NUM 8
#define D_DIM 64
#define B_NUM 4
#define N_SEQ 2048
#define M_TOT (B_NUM*N_SEQ)   // 8192

typedef unsigned short u16;
typedef unsigned int   u32;
typedef __attribute__((ext_vector_type(8))) short short8;
typedef __attribute__((ext_vector_type(4))) float f32x4;

#define MFMA16 __builtin_amdgcn_mfma_f32_16x16x32_bf16

__device__ __forceinline__ u16 f2b(float f) {          // RNE
    union { float f; u32 u; } v; v.f = f;
    u32 r = v.u + 0x7FFFu + ((v.u >> 16) & 1u);
    return (u16)(r >> 16);
}
__device__ __forceinline__ float fexp2(float x) {      // raw v_exp_f32 (2^x)
    float r;
    asm("v_exp_f32 %0, %1" : "=v"(r) : "v"(x));
    return r;
}
__device__ __forceinline__ float b2f_lo(u32 u) {
    union { u32 u; float f; } v; v.u = u << 16; return v.f;
}
__device__ __forceinline__ float b2f_hi(u32 u) {
    union { u32 u; float f; } v; v.u = u & 0xFFFF0000u; return v.f;
}
__device__ __forceinline__ void gload16(const u16* g, u16* l) {
    __builtin_amdgcn_global_load_lds(
        (const __attribute__((address_space(1))) void*)g,
        (__attribute__((address_space(3))) void*)l, 16, 0, 0);
}
__device__ __forceinline__ void cast8(const float* s, u16* d) {
    const float4* p = (const float4*)s;
    float4 a = p[0], b = p[1];
    short8 v;
    v[0] = (short)f2b(a.x); v[1] = (short)f2b(a.y);
    v[2] = (short)f2b(a.z); v[3] = (short)f2b(a.w);
    v[4] = (short)f2b(b.x); v[5] = (short)f2b(b.y);
    v[6] = (short)f2b(b.z); v[7] = (short)f2b(b.w);
    *(short8*)d = v;
}

// ---------------------------------------------------------------------------
// k_prep: cast X, cast W (packed [2048][512]), bias-vector concat.
// (bias matrix moved into the QKV GEMM launch for overlap)
// ---------------------------------------------------------------------------
__global__ __launch_bounds__(256) void k_prep(const float* __restrict__ qc,
                                              const float* __restrict__ Wq,
                                              const float* __restrict__ Wk,
                                              const float* __restrict__ Wv,
                                              const float* __restrict__ Wo,
                                              const float* __restrict__ bq,
                                              const float* __restrict__ bk,
                                              const float* __restrict__ bv,
                                              const float* __restrict__ bo,
                                              u16* __restrict__ xb,
                                              u16* __restrict__ wb,
                                              float* __restrict__ bqkv)
{
    const int bid = blockIdx.x, t = threadIdx.x;
    if (bid < 2048) {
        int i = bid * 256 + t;
        cast8(qc + (size_t)i * 8, xb + (size_t)i * 8);
    } else if (bid < 2560) {
        int r = bid - 2048;
        int y = r >> 7;
        const float* s = (y == 0) ? Wq : (y == 1) ? Wk : (y == 2) ? Wv : Wo;
        int i = (r & 127) * 256 + t;
        cast8(s + (size_t)i * 8, wb + (size_t)y * 262144 + (size_t)i * 8);
    } else {
        int idx = (bid - 2560) * 256 + t;
        float v = idx < 512 ? bq[idx] : idx < 1024 ? bk[idx - 512]
                : idx < 1536 ? bv[idx - 1024] : bo[idx - 1536];
        bqkv[idx] = v;
    }
}

// ---------------------------------------------------------------------------
// Unified NT GEMM: tile 256x128, BK=32, 8 waves (4m x 2n, 64x64 wave tile),
// triple-buffered 72KB LDS, one barrier per step, counted vmcnt(3)
// (R9-proven schedule, 3 gloads/thread/step). XCD-bijective swizzle.
// fixed_mode==3 -> fp32 h = acc + bias + qc (grid 128). fixed_mode==-1 ->
// grid 4480: blocks [0,384) QKV GEMM (mode=n0>>9: 0->Q,1->K,2->V^T),
// blocks [384,4480) compute the bias matrix (overlapped, independent).
// Modes 0/1/2 use the coalesced LDS-staged epilogue (R11-proven).
// ---------------------------------------------------------------------------
__global__ __launch_bounds__(512, 2) void k_gemm(const u16* __restrict__ A,
                                                 const u16* __restrict__ Bw,
                                                 const float* __restrict__ bias,
                                                 const float* __restrict__ qc,
                                                 u16* __restrict__ oq,
                                                 u16* __restrict__ ok,
                                                 u16* __restrict__ ov,
                                                 float* __restrict__ outf,
                                                 int fixed_mode,
                                                 const float* __restrict__ qpos,
                                                 u16* __restrict__ biasm)
{
    __shared__ alignas(16) u16 smem[36864];        // 72 KB
    const int bid = blockIdx.x, t = threadIdx.x;

    if (fixed_mode == -1 && bid >= 384) {
        // ---- bias matrix region: 4096 blocks x 512 thr = 2 rows/block ----
        int ig = (bid - 384) * 2 + (t >> 8);       // global row in [0, 8192)
        int i = ig & 2047, b = ig >> 11;
        int j8 = t & 255;
        const float4 qi = *(const float4*)(qpos + (size_t)(b * 2048 + i) * 4);
        const float4* pj = (const float4*)(qpos + ((size_t)b * 2048 + j8 * 8) * 4);
        const float NC = -0.1f * 1.4426950408889634f;
        short8 v;
        #pragma unroll
        for (int jj = 0; jj < 8; ++jj) {
            float4 pk = pj[jj];
            float dx = qi.x - pk.x, dy = qi.y - pk.y;
            float d2 = fmaf(dx, dx, fmaf(dy, dy, 1e-8f));
            v[jj] = (short)f2b(sqrtf(d2) * NC);
        }
        *(short8*)(biasm + (size_t)(b * 2048 + i) * 2048 + j8 * 8) = v;
        return;
    }

    u16* laB = smem;                               // 3 x [4][256][8] (8192 each)
    u16* lbB = smem + 24576;                       // 3 x [4][128][8] (4096 each)
    const int nwg = (fixed_mode == 3) ? 128 : 384;
    const int ntn = (fixed_mode == 3) ? 4 : 12;
    const int swz = (bid & 7) * (nwg >> 3) + (bid >> 3);
    const int m0 = (swz / ntn) * 256, n0 = (swz % ntn) * 128;
    const int w = t >> 6, l = t & 63, lr = l & 15, kg = l >> 4;
    const int wm = w >> 1, wn = w & 1;
    const int NS = C_DIM / 32;                     // 16 K-steps

    f32x4 acc[4][4] = {};

    // staging coords: A 256x32 (2 issues), B 128x32 (1 issue)
    const int arow = t & 255, akoct = t >> 8;      // issue j adds koct 2j
    const int brow = t & 127, bkoct = t >> 7;
    const u16* As0 = A + (size_t)(m0 + arow) * C_DIM + akoct * 8;
    const u16* Bs0 = Bw + (size_t)(n0 + brow) * C_DIM + bkoct * 8;

#define GSTAGE(buf, k0) { \
    u16* ldA = laB + (buf) * 8192; \
    u16* ldB = lbB + (buf) * 4096; \
    gload16(As0 + (k0),      ldA + w * 512); \
    gload16(As0 + (k0) + 16, ldA + 4096 + w * 512); \
    gload16(Bs0 + (k0),      ldB + w * 512); }

    GSTAGE(0, 0)
    GSTAGE(1, 32)
    asm volatile("s_waitcnt vmcnt(3)" ::: "memory");
    __builtin_amdgcn_s_barrier();

    for (int s = 0; s < NS; ++s) {
        const int bi = s % 3;
        if (s + 2 < NS) {
            const int bn = (s + 2) % 3;
            GSTAGE(bn, (s + 2) * 32)
        }
        __builtin_amdgcn_sched_barrier(0);

        const u16* laS = laB + bi * 8192 + kg * 2048;
        const u16* lbS = lbB + bi * 4096 + kg * 1024;
        short8 af[4], bf[4];
        #pragma unroll
        for (int fm = 0; fm < 4; ++fm)
            af[fm] = *(const short8*)(laS + (wm * 64 + fm * 16 + lr) * 8);
        #pragma unroll
        for (int fn = 0; fn < 4; ++fn)
            bf[fn] = *(const short8*)(lbS + (wn * 64 + fn * 16 + lr) * 8);
        __builtin_amdgcn_s_setprio(1);
        #pragma unroll
        for (int fm = 0; fm < 4; ++fm)
        #pragma unroll
        for (int fn = 0; fn < 4; ++fn)
            acc[fm][fn] = MFMA16(af[fm], bf[fn], acc[fm][fn], 0, 0, 0);
        __builtin_amdgcn_s_setprio(0);

        if (s + 1 < NS) {
            if (s + 2 < NS) asm volatile("s_waitcnt vmcnt(3)" ::: "memory");
            else            asm volatile("s_waitcnt vmcnt(0)" ::: "memory");
            __builtin_amdgcn_s_barrier();
        }
    }
#undef GSTAGE

    const int mode = (fixed_mode == 3) ? 3 : (n0 >> 9);

    if (mode == 3) {
        #pragma unroll
        for (int fm = 0; fm < 4; ++fm)
        #pragma unroll
        for (int fn = 0; fn < 4; ++fn) {
            int c = n0 + wn * 64 + fn * 16 + lr;
            float bv_ = bias[c];
            #pragma unroll
            for (int i = 0; i < 4; ++i) {
                int m = m0 + wm * 64 + fm * 16 + kg * 4 + i;
                outf[(size_t)m * C_DIM + c] = acc[fm][fn][i] + bv_ + qc[(size_t)m * C_DIM + c];
            }
        }
        return;
    }

    // ---- coalesced epilogue via LDS staging (R11-proven pattern) ----
    __syncthreads();

    if (mode == 2) {
        u16 (*tb)[260] = (u16(*)[260])smem;        // [128][260] = 66.5 KB
        #pragma unroll
        for (int fm = 0; fm < 4; ++fm)
        #pragma unroll
        for (int fn = 0; fn < 4; ++fn) {
            int c_loc = wn * 64 + fn * 16 + lr;
            float bv_ = bias[n0 + c_loc];
            #pragma unroll
            for (int i = 0; i < 4; ++i) {
                int m_loc = wm * 64 + fm * 16 + kg * 4 + i;
                tb[c_loc][m_loc] = f2b(acc[fm][fn][i] + bv_);
            }
        }
        __syncthreads();
        const int bb = m0 >> 11, nb = m0 & 2047;
        #pragma unroll
        for (int p = 0; p < 8; ++p) {
            int id = p * 512 + t;                  // 0..4095
            int row = id >> 5, seg = id & 31;      // row = c_loc, seg along m
            short8 v = *(const short8*)&tb[row][seg * 8];
            int cc = (n0 & 511) + row;
            int h = cc >> 6, d = cc & 63;
            *(short8*)(ov + ((size_t)(bb * H_NUM + h) * D_DIM + d) * N_SEQ
                       + nb + seg * 8) = v;
        }
    } else {
        u16* outb = (mode == 0) ? oq : ok;
        u16 (*tb)[132] = (u16(*)[132])smem;        // [256][132] = 67.6 KB
        #pragma unroll
        for (int fm = 0; fm < 4; ++fm)
        #pragma unroll
        for (int fn = 0; fn < 4; ++fn) {
            int c_loc = wn * 64 + fn * 16 + lr;
            float bv_ = bias[n0 + c_loc];
            #pragma unroll
            for (int i = 0; i < 4; ++i) {
                int m_loc = wm * 64 + fm * 16 + kg * 4 + i;
                tb[m_loc][c_loc] = f2b(acc[fm][fn][i] + bv_);
            }
        }
        __syncthreads();
        const int bb = m0 >> 11;
        #pragma unroll
        for (int p = 0; p < 8; ++p) {
            int id = p * 512 + t;                  // 0..4095
            int row = id >> 4, seg = id & 15;      // row = m_loc, seg along c
            short8 v = *(const short8*)&tb[row][seg * 8];
            int m = m0 + row, n = m & 2047;
            int cc = (n0 & 511) + seg * 8;
            int h = cc >> 6, d = cc & 63;
            *(short8*)(outb + ((size_t)(bb * H_NUM + h) * N_SEQ + n) * D_DIM + d) = v;
        }
    }
}

// ---------------------------------------------------------------------------
// Flash attention (R9-proven, byte-identical): block = one (b,h) x 128
// q-rows, 8 waves x 16 q. Triple-buffered K/V^T via global_load_lds, counted
// vmcnt, XOR-swizzled 16B slots. Swapped-operand S^T = mfma(K,Q). Fixed-shift
// softmax (exact: log2-domain scores bounded). setprio on MFMA.
// ---------------------------------------------------------------------------
__global__ __launch_bounds__(512, 4) void k_flash(const u16* __restrict__ Q,
                                                  const u16* __restrict__ K,
                                                  const u16* __restrict__ Vt,
                                                  const u16* __restrict__ bias,
                                                  u16* __restrict__ attn_out)
{
    __shared__ alignas(16) u16 kbuf[3][64][64];   // [key][d], slot-swizzled
    __shared__ alignas(16) u16 vbuf[3][64][64];   // [d][key], slot-swizzled
    __shared__ alignas(16) u16 pbuf[8][16][64];   // per-wave P, swizzled

    const int t = threadIdx.x;
    const int w = t >> 6, l = t & 63, lr = l & 15, g = l >> 4;
    const int flat = blockIdx.y * 16 + blockIdx.x;
    const int h = flat >> 6, b = (flat >> 4) & 3, qt = flat & 15;
    const int bh = b * H_NUM + h;
    const int q = qt * 128 + w * 16 + lr;
    const int sx = lr & 7;

    const float SC = 0.125f * 1.4426950408889634f;
    const int NT = N_SEQ / 64;

    const u16* Qb = Q + ((size_t)bh * N_SEQ + q) * D_DIM;
    const u16* Kb = K + (size_t)bh * N_SEQ * D_DIM;
    const u16* Vb = Vt + (size_t)bh * D_DIM * N_SEQ;
    const u16* Bb = bias + ((size_t)b * N_SEQ + q) * N_SEQ;

    short8 aq0 = *(const short8*)(Qb + g * 8);
    short8 aq1 = *(const short8*)(Qb + 32 + g * 8);

    const int sr = t >> 3;
    const int ssl = (t & 7) ^ (sr & 7);
    const u16* gK = Kb + (size_t)sr * D_DIM + ssl * 8;
    const u16* gV = Vb + (size_t)sr * N_SEQ + ssl * 8;

    f32x4 acc[4] = {};
    float lac0 = 0.f, lac1 = 0.f, lac2 = 0.f, lac3 = 0.f;
    uint2 bcur[4], bnxt[4];

    gload16(gK,              (u16*)&kbuf[0][0][0] + w * 512);
    gload16(gV,              (u16*)&vbuf[0][0][0] + w * 512);
    gload16(gK + 64 * D_DIM, (u16*)&kbuf[1][0][0] + w * 512);
    gload16(gV + 64,         (u16*)&vbuf[1][0][0] + w * 512);
    __builtin_amdgcn_sched_barrier(0);
    #pragma unroll
    for (int fn = 0; fn < 4; ++fn)
        bcur[fn] = *(const uint2*)(Bb + fn * 16 + g * 4);
    __builtin_amdgcn_sched_barrier(0);
    asm volatile("s_waitcnt vmcnt(6)" ::: "memory");
    __builtin_amdgcn_s_barrier();

    for (int kt = 0; kt < NT; ++kt) {
        const int bi = kt % 3;
        if (kt + 1 < NT) {
            #pragma unroll
            for (int fn = 0; fn < 4; ++fn)
                bnxt[fn] = *(const uint2*)(Bb + (kt + 1) * 64 + fn * 16 + g * 4);
        }
        __builtin_amdgcn_sched_barrier(0);
        if (kt + 2 < NT) {
            const int bn = (kt + 2) % 3;
            gload16(gK + (size_t)(kt + 2) * 64 * D_DIM, (u16*)&kbuf[bn][0][0] + w * 512);
            gload16(gV + (kt + 2) * 64,                 (u16*)&vbuf[bn][0][0] + w * 512);
        }
        __builtin_amdgcn_sched_barrier(0);

        f32x4 st[4] = {};
        __builtin_amdgcn_s_setprio(1);
        #pragma unroll
        for (int fn = 0; fn < 4; ++fn) {
            short8 ak0 = *(const short8*)&kbuf[bi][fn * 16 + lr][(g ^ sx) * 8];
            short8 ak1 = *(const short8*)&kbuf[bi][fn * 16 + lr][((4 + g) ^ sx) * 8];
            st[fn] = MFMA16(ak0, aq0, st[fn], 0, 0, 0);
            st[fn] = MFMA16(ak1, aq1, st[fn], 0, 0, 0);
        }
        __builtin_amdgcn_s_setprio(0);

        float sv[16];
        #pragma unroll
        for (int fn = 0; fn < 4; ++fn) {
            sv[fn * 4 + 0] = fmaf(st[fn][0], SC, b2f_lo(bcur[fn].x));
            sv[fn * 4 + 1] = fmaf(st[fn][1], SC, b2f_hi(bcur[fn].x));
            sv[fn * 4 + 2] = fmaf(st[fn][2], SC, b2f_lo(bcur[fn].y));
            sv[fn * 4 + 3] = fmaf(st[fn][3], SC, b2f_hi(bcur[fn].y));
        }
        #pragma unroll
        for (int j = 0; j < 4; ++j)  { sv[j]  = fexp2(sv[j]);  lac0 += sv[j]; }
        #pragma unroll
        for (int j = 4; j < 8; ++j)  { sv[j]  = fexp2(sv[j]);  lac1 += sv[j]; }
        #pragma unroll
        for (int j = 8; j < 12; ++j) { sv[j]  = fexp2(sv[j]);  lac2 += sv[j]; }
        #pragma unroll
        for (int j = 12; j < 16; ++j){ sv[j]  = fexp2(sv[j]);  lac3 += sv[j]; }

        #pragma unroll
        for (int fn = 0; fn < 4; ++fn) {
            union { float f; u32 u; } p0, p1, p2, p3;
            p0.f = sv[fn * 4 + 0]; p1.f = sv[fn * 4 + 1];
            p2.f = sv[fn * 4 + 2]; p3.f = sv[fn * 4 + 3];
            uint2 pk;
            pk.x = (p1.u & 0xFFFF0000u) | (p0.u >> 16);
            pk.y = (p3.u & 0xFFFF0000u) | (p2.u >> 16);
            int slot = fn * 2 + (g >> 1);
            *(uint2*)&pbuf[w][lr][(slot ^ sx) * 8 + (g & 1) * 4] = pk;
        }
        asm volatile("s_waitcnt lgkmcnt(0)" ::: "memory");
        __builtin_amdgcn_sched_barrier(0);

        short8 bp0 = *(const short8*)&pbuf[w][lr][(g ^ sx) * 8];
        short8 bp1 = *(const short8*)&pbuf[w][lr][((4 + g) ^ sx) * 8];

        __builtin_amdgcn_s_setprio(1);
        #pragma unroll
        for (int df = 0; df < 4; ++df) {
            short8 av0 = *(const short8*)&vbuf[bi][df * 16 + lr][(g ^ sx) * 8];
            short8 av1 = *(const short8*)&vbuf[bi][df * 16 + lr][((4 + g) ^ sx) * 8];
            acc[df] = MFMA16(av0, bp0, acc[df], 0, 0, 0);
            acc[df] = MFMA16(av1, bp1, acc[df], 0, 0, 0);
        }
        __builtin_amdgcn_s_setprio(0);

        #pragma unroll
        for (int fn = 0; fn < 4; ++fn) bcur[fn] = bnxt[fn];

        if (kt + 1 < NT) {
            if (kt + 2 < NT) asm volatile("s_waitcnt vmcnt(6)" ::: "memory");
            else             asm volatile("s_waitcnt vmcnt(4)" ::: "memory");
            __builtin_amdgcn_s_barrier();
        }
    }

    float l_run = (lac0 + lac1) + (lac2 + lac3);
    l_run += __shfl_xor(l_run, 16);
    l_run += __shfl_xor(l_run, 32);
    float rl;
    asm("v_rcp_f32 %0, %1" : "=v"(rl) : "v"(l_run));
    rl = rl * (2.f - l_run * rl);
    u16* ob = attn_out + ((size_t)(b * N_SEQ + q)) * C_DIM + h * D_DIM + g * 4;
    #pragma unroll
    for (int df = 0; df < 4; ++df) {
        u32 w0 = ((u32)f2b(acc[df][1] * rl) << 16) | f2b(acc[df][0] * rl);
        u32 w1 = ((u32)f2b(acc[df][3] * rl) << 16) | f2b(acc[df][2] * rl);
        uint2 pk; pk.x = w0; pk.y = w1;
        *(uint2*)(ob + df * 16) = pk;
    }
}

// ---------------------------------------------------------------------------
// LayerNorm over h (residual already fused). float2 loads. (unchanged)
// ---------------------------------------------------------------------------
__global__ __launch_bounds__(256) void k_ln(const float* __restrict__ hbuf,
                                            const float* __restrict__ gamma,
                                            const float* __restrict__ beta,
                                            float* __restrict__ out)
{
    const int r = blockIdx.x;
    const int t = threadIdx.x;
    const size_t base = (size_t)r * C_DIM;
    float2 h01 = *(const float2*)(hbuf + base + t * 2);
    float s = h01.x + h01.y, sq = h01.x * h01.x + h01.y * h01.y;
    #pragma unroll
    for (int m = 1; m < 64; m <<= 1) {
        s += __shfl_xor(s, m);
        sq += __shfl_xor(sq, m);
    }
    __shared__ float ss[4], ssq[4];
    int w = t >> 6;
    if ((t & 63) == 0) { ss[w] = s; ssq[w] = sq; }
    __syncthreads();
    s = ss[0] + ss[1] + ss[2] + ss[3];
    sq = ssq[0] + ssq[1] + ssq[2] + ssq[3];
    float mu = s * (1.f / C_DIM);
    float var = sq * (1.f / C_DIM) - mu * mu;
    float inv = rsqrtf(var + 1e-5f);
    float2 g01 = *(const float2*)(gamma + t * 2);
    float2 b01 = *(const float2*)(beta + t * 2);
    float2 o;
    o.x = (h01.x - mu) * inv * g01.x + b01.x;
    o.y = (h01.y - mu) * inv * g01.y + b01.y;
    *(float2*)(out + base + t * 2) = o;
}

// ---------------------------------------------------------------------------
extern "C" void kernel_launch(void* const* d_in, const int* in_sizes, int n_in,
                              void* d_out, int out_size, void* d_ws, size_t ws_size,
                              hipStream_t stream)
{
    const float* qc    = (const float*)d_in[0];
    const float* qpos  = (const float*)d_in[1];
    const float* Wq    = (const float*)d_in[2];
    const float* bq    = (const float*)d_in[3];
    const float* Wk    = (const float*)d_in[4];
    const float* bk    = (const float*)d_in[5];
    const float* Wv    = (const float*)d_in[6];
    const float* bv    = (const float*)d_in[7];
    const float* Wo    = (const float*)d_in[8];
    const float* bo    = (const float*)d_in[9];
    const float* gamma = (const float*)d_in[10];
    const float* beta  = (const float*)d_in[11];
    float* out = (float*)d_out;

    char* ws = (char*)d_ws;
    const size_t MB = 1024 * 1024;
    u16*   bias_ws = (u16*)(ws);                   // 32 MB bf16 [4][2048][2048]
    u16*   xb_ws   = (u16*)(ws + 32 * MB);         //  8 MB bf16 X
    u16*   wb_ws   = (u16*)(ws + 40 * MB);         //  2 MB bf16 [2048][512]
    float* bqkv_ws = (float*)(ws + 42 * MB);       //  8 KB fp32 bq|bk|bv|bo
    u16*   q_ws    = (u16*)(ws + 43 * MB);         //  8 MB bf16 Q [B][H][N][D]
    u16*   k_ws    = (u16*)(ws + 51 * MB);         //  8 MB bf16 K [B][H][N][D]
    u16*   v_ws    = (u16*)(ws + 59 * MB);         //  8 MB bf16 V [B][H][D][N]
    u16*   a_ws    = (u16*)(ws + 75 * MB);         //  8 MB bf16 attn out
    float* p_ws    = (float*)(ws + 43 * MB);       // 16 MB fp32 h (aliases q/k: dead)

    k_prep<<<dim3(2568), 256, 0, stream>>>(qc, Wq, Wk, Wv, Wo, bq, bk, bv, bo,
                                           xb_ws, wb_ws, bqkv_ws);
    k_gemm<<<dim3(4480), 512, 0, stream>>>(xb_ws, wb_ws, bqkv_ws, nullptr,
                                           q_ws, k_ws, v_ws, nullptr, -1,
                                           qpos, bias_ws);
    k_flash<<<dim3(16, 32), 512, 0, stream>>>(q_ws, k_ws, v_ws, bias_ws, a_ws);
    k_gemm<<<dim3(128), 512, 0, stream>>>(a_ws, wb_ws + 1536 * 512,
                                          bqkv_ws + 1536, qc,
                                          nullptr, nullptr, nullptr, p_ws, 3,
                                          nullptr, nullptr);
    k_ln<<<dim3(M_TOT), 256, 0, stream>>>(p_ws, gamma, beta, out);
}

// Round 13
// 161.667 us; speedup vs baseline: 1.0532x; 1.0532x over previous
//
#include <hip/hip_runtime.h>
#include <hip/hip_bf16.h>

#define C_DIM 512
#define H_NUM 8
#define D_DIM 64
#define B_NUM 4
#define N_SEQ 2048
#define M_TOT (B_NUM*N_SEQ)   // 8192

typedef unsigned short u16;
typedef unsigned int   u32;
typedef __attribute__((ext_vector_type(8))) short short8;
typedef __attribute__((ext_vector_type(4))) float f32x4;

#define MFMA16 __builtin_amdgcn_mfma_f32_16x16x32_bf16

__device__ __forceinline__ u16 f2b(float f) {          // RNE
    union { float f; u32 u; } v; v.f = f;
    u32 r = v.u + 0x7FFFu + ((v.u >> 16) & 1u);
    return (u16)(r >> 16);
}
__device__ __forceinline__ float fexp2(float x) {      // raw v_exp_f32 (2^x)
    float r;
    asm("v_exp_f32 %0, %1" : "=v"(r) : "v"(x));
    return r;
}
__device__ __forceinline__ float b2f_lo(u32 u) {
    union { u32 u; float f; } v; v.u = u << 16; return v.f;
}
__device__ __forceinline__ float b2f_hi(u32 u) {
    union { u32 u; float f; } v; v.u = u & 0xFFFF0000u; return v.f;
}
__device__ __forceinline__ void gload16(const u16* g, u16* l) {
    __builtin_amdgcn_global_load_lds(
        (const __attribute__((address_space(1))) void*)g,
        (__attribute__((address_space(3))) void*)l, 16, 0, 0);
}
__device__ __forceinline__ void cast8(const float* s, u16* d) {
    const float4* p = (const float4*)s;
    float4 a = p[0], b = p[1];
    short8 v;
    v[0] = (short)f2b(a.x); v[1] = (short)f2b(a.y);
    v[2] = (short)f2b(a.z); v[3] = (short)f2b(a.w);
    v[4] = (short)f2b(b.x); v[5] = (short)f2b(b.y);
    v[6] = (short)f2b(b.z); v[7] = (short)f2b(b.w);
    *(short8*)d = v;
}

// ---------------------------------------------------------------------------
// k_prep: fused cast X, cast W (packed [2048][512]), bias-vector concat,
// and bias matrix precompute. Region by blockIdx.x. (R11-proven)
// ---------------------------------------------------------------------------
__global__ __launch_bounds__(256) void k_prep(const float* __restrict__ qc,
                                              const float* __restrict__ Wq,
                                              const float* __restrict__ Wk,
                                              const float* __restrict__ Wv,
                                              const float* __restrict__ Wo,
                                              const float* __restrict__ bq,
                                              const float* __restrict__ bk,
                                              const float* __restrict__ bv,
                                              const float* __restrict__ bo,
                                              const float* __restrict__ qpos,
                                              u16* __restrict__ xb,
                                              u16* __restrict__ wb,
                                              float* __restrict__ bqkv,
                                              u16* __restrict__ bias)
{
    const int bid = blockIdx.x, t = threadIdx.x;
    if (bid < 2048) {
        int i = bid * 256 + t;
        cast8(qc + (size_t)i * 8, xb + (size_t)i * 8);
    } else if (bid < 2560) {
        int r = bid - 2048;
        int y = r >> 7;
        const float* s = (y == 0) ? Wq : (y == 1) ? Wk : (y == 2) ? Wv : Wo;
        int i = (r & 127) * 256 + t;
        cast8(s + (size_t)i * 8, wb + (size_t)y * 262144 + (size_t)i * 8);
    } else if (bid < 2568) {
        int idx = (bid - 2560) * 256 + t;
        float v = idx < 512 ? bq[idx] : idx < 1024 ? bk[idx - 512]
                : idx < 1536 ? bv[idx - 1024] : bo[idx - 1536];
        bqkv[idx] = v;
    } else {
        int r = bid - 2568;                    // [0, 8192)
        int i = r & 2047, b = r >> 11;
        const float4 qi = *(const float4*)(qpos + (size_t)(b * 2048 + i) * 4);
        const float4* pj = (const float4*)(qpos + ((size_t)b * 2048 + t * 8) * 4);
        const float NC = -0.1f * 1.4426950408889634f;
        short8 v;
        #pragma unroll
        for (int jj = 0; jj < 8; ++jj) {
            float4 pk = pj[jj];
            float dx = qi.x - pk.x, dy = qi.y - pk.y;
            float d2 = fmaf(dx, dx, fmaf(dy, dy, 1e-8f));
            v[jj] = (short)f2b(sqrtf(d2) * NC);
        }
        *(short8*)(bias + (size_t)(b * 2048 + i) * 2048 + t * 8) = v;
    }
}

// ---------------------------------------------------------------------------
// Unified NT GEMM (R11-proven, byte-identical): tile 128x128, BK=32, triple-
// buffered LDS, one barrier per step, counted vmcnt(4). Coalesced epilogue
// for modes 0/1/2 via LDS staging; mode 3 = fp32 h = acc + bias + qc.
// ---------------------------------------------------------------------------
__global__ __launch_bounds__(256) void k_gemm(const u16* __restrict__ A,
                                              const u16* __restrict__ Bw,
                                              const float* __restrict__ bias,
                                              const float* __restrict__ qc,
                                              u16* __restrict__ oq,
                                              u16* __restrict__ ok,
                                              u16* __restrict__ ov,
                                              float* __restrict__ outf,
                                              int fixed_mode)
{
    __shared__ alignas(16) u16 smem[24576];        // 48 KB, aliased below
    typedef u16 (*Tbuf)[4][128][8];
    Tbuf la = (Tbuf)smem;                          // [3][4][128][8]
    Tbuf lb = (Tbuf)(smem + 12288);
    const int t = threadIdx.x;
    const int nwg = gridDim.x * gridDim.y;
    const int wgid = blockIdx.y * gridDim.x + blockIdx.x;
    const int swz = (wgid & 7) * (nwg >> 3) + (wgid >> 3);
    const int ntn = gridDim.y;
    const int m0 = (swz / ntn) * 128, n0 = (swz % ntn) * 128;
    const int w = t >> 6, l = t & 63, lr = l & 15, kg = l >> 4;
    const int wm = w >> 1, wn = w & 1;
    const int NS = C_DIM / 32;

    f32x4 acc[4][4] = {};

    const int srow = t & 127;
    const u16* As0 = A + (size_t)(m0 + srow) * C_DIM + (t >> 7) * 8;
    const u16* Bs0 = Bw + (size_t)(n0 + srow) * C_DIM + (t >> 7) * 8;

    #pragma unroll
    for (int s = 0; s < 2; ++s) {
        u16* ldA = (u16*)la[s] + w * 512;
        u16* ldB = (u16*)lb[s] + w * 512;
        gload16(As0 + s * 32,      ldA);
        gload16(As0 + s * 32 + 16, ldA + 2048);
        gload16(Bs0 + s * 32,      ldB);
        gload16(Bs0 + s * 32 + 16, ldB + 2048);
    }
    asm volatile("s_waitcnt vmcnt(4)" ::: "memory");
    __builtin_amdgcn_s_barrier();

    for (int s = 0; s < NS; ++s) {
        const int bi = s % 3;
        if (s + 2 < NS) {
            const int bn = (s + 2) % 3;
            u16* ldA = (u16*)la[bn] + w * 512;
            u16* ldB = (u16*)lb[bn] + w * 512;
            gload16(As0 + (s + 2) * 32,      ldA);
            gload16(As0 + (s + 2) * 32 + 16, ldA + 2048);
            gload16(Bs0 + (s + 2) * 32,      ldB);
            gload16(Bs0 + (s + 2) * 32 + 16, ldB + 2048);
        }
        __builtin_amdgcn_sched_barrier(0);

        short8 af[4], bf[4];
        #pragma unroll
        for (int fm = 0; fm < 4; ++fm)
            af[fm] = *(const short8*)la[bi][kg][wm * 64 + fm * 16 + lr];
        #pragma unroll
        for (int fn = 0; fn < 4; ++fn)
            bf[fn] = *(const short8*)lb[bi][kg][wn * 64 + fn * 16 + lr];
        __builtin_amdgcn_s_setprio(1);
        #pragma unroll
        for (int fm = 0; fm < 4; ++fm)
        #pragma unroll
        for (int fn = 0; fn < 4; ++fn)
            acc[fm][fn] = MFMA16(af[fm], bf[fn], acc[fm][fn], 0, 0, 0);
        __builtin_amdgcn_s_setprio(0);

        if (s + 1 < NS) {
            if (s + 2 < NS) asm volatile("s_waitcnt vmcnt(4)" ::: "memory");
            else            asm volatile("s_waitcnt vmcnt(0)" ::: "memory");
            __builtin_amdgcn_s_barrier();
        }
    }

    const int mode = (fixed_mode == 3) ? 3 : (n0 >> 9);

    if (mode == 3) {
        #pragma unroll
        for (int fm = 0; fm < 4; ++fm)
        #pragma unroll
        for (int fn = 0; fn < 4; ++fn) {
            int c = n0 + wn * 64 + fn * 16 + lr;
            float bv_ = bias[c];
            #pragma unroll
            for (int i = 0; i < 4; ++i) {
                int m = m0 + wm * 64 + fm * 16 + kg * 4 + i;
                outf[(size_t)m * C_DIM + c] = acc[fm][fn][i] + bv_ + qc[(size_t)m * C_DIM + c];
            }
        }
        return;
    }

    // ---- coalesced epilogue: stage tile to LDS (pad 132), b128 stores ----
    __syncthreads();                               // LDS reuse safe
    u16 (*tb)[132] = (u16(*)[132])smem;            // [128][132] = 33 KB

    if (mode == 2) {
        // stage transposed: tb[c_loc][m_loc]
        #pragma unroll
        for (int fm = 0; fm < 4; ++fm)
        #pragma unroll
        for (int fn = 0; fn < 4; ++fn) {
            int c_loc = wn * 64 + fn * 16 + lr;
            float bv_ = bias[n0 + c_loc];
            #pragma unroll
            for (int i = 0; i < 4; ++i) {
                int m_loc = wm * 64 + fm * 16 + kg * 4 + i;
                tb[c_loc][m_loc] = f2b(acc[fm][fn][i] + bv_);
            }
        }
        __syncthreads();
        const int bb = m0 >> 11, nb = m0 & 2047;
        #pragma unroll
        for (int p = 0; p < 8; ++p) {
            int id = p * 256 + t;                  // 0..2047
            int row = id >> 4, seg = id & 15;      // row = c_loc, seg along m
            short8 v = *(const short8*)&tb[row][seg * 8];
            int cc = (n0 & 511) + row;
            int h = cc >> 6, d = cc & 63;
            *(short8*)(ov + ((size_t)(bb * H_NUM + h) * D_DIM + d) * N_SEQ
                       + nb + seg * 8) = v;
        }
    } else {
        u16* outb = (mode == 0) ? oq : ok;
        // stage natural: tb[m_loc][c_loc]
        #pragma unroll
        for (int fm = 0; fm < 4; ++fm)
        #pragma unroll
        for (int fn = 0; fn < 4; ++fn) {
            int c_loc = wn * 64 + fn * 16 + lr;
            float bv_ = bias[n0 + c_loc];
            #pragma unroll
            for (int i = 0; i < 4; ++i) {
                int m_loc = wm * 64 + fm * 16 + kg * 4 + i;
                tb[m_loc][c_loc] = f2b(acc[fm][fn][i] + bv_);
            }
        }
        __syncthreads();
        const int bb = m0 >> 11;
        #pragma unroll
        for (int p = 0; p < 8; ++p) {
            int id = p * 256 + t;
            int row = id >> 4, seg = id & 15;      // row = m_loc, seg along c
            short8 v = *(const short8*)&tb[row][seg * 8];
            int m = m0 + row, n = m & 2047;
            int cc = (n0 & 511) + seg * 8;
            int h = cc >> 6, d = cc & 63;
            *(short8*)(outb + ((size_t)(bb * H_NUM + h) * N_SEQ + n) * D_DIM + d) = v;
        }
    }
}

// ---------------------------------------------------------------------------
// Flash attention (R9/R11-proven, byte-identical): block = one (b,h) x 128
// q-rows, 8 waves x 16 q. Triple-buffered K/V^T via global_load_lds, counted
// vmcnt, XOR-swizzled 16B slots. Swapped-operand S^T = mfma(K,Q). Fixed-shift
// softmax (exact: log2-domain scores bounded). setprio on MFMA.
// ---------------------------------------------------------------------------
__global__ __launch_bounds__(512, 4) void k_flash(const u16* __restrict__ Q,
                                                  const u16* __restrict__ K,
                                                  const u16* __restrict__ Vt,
                                                  const u16* __restrict__ bias,
                                                  u16* __restrict__ attn_out)
{
    __shared__ alignas(16) u16 kbuf[3][64][64];   // [key][d], slot-swizzled
    __shared__ alignas(16) u16 vbuf[3][64][64];   // [d][key], slot-swizzled
    __shared__ alignas(16) u16 pbuf[8][16][64];   // per-wave P, swizzled

    const int t = threadIdx.x;
    const int w = t >> 6, l = t & 63, lr = l & 15, g = l >> 4;
    const int flat = blockIdx.y * 16 + blockIdx.x;
    const int h = flat >> 6, b = (flat >> 4) & 3, qt = flat & 15;
    const int bh = b * H_NUM + h;
    const int q = qt * 128 + w * 16 + lr;
    const int sx = lr & 7;

    const float SC = 0.125f * 1.4426950408889634f;
    const int NT = N_SEQ / 64;

    const u16* Qb = Q + ((size_t)bh * N_SEQ + q) * D_DIM;
    const u16* Kb = K + (size_t)bh * N_SEQ * D_DIM;
    const u16* Vb = Vt + (size_t)bh * D_DIM * N_SEQ;
    const u16* Bb = bias + ((size_t)b * N_SEQ + q) * N_SEQ;

    short8 aq0 = *(const short8*)(Qb + g * 8);
    short8 aq1 = *(const short8*)(Qb + 32 + g * 8);

    const int sr = t >> 3;
    const int ssl = (t & 7) ^ (sr & 7);
    const u16* gK = Kb + (size_t)sr * D_DIM + ssl * 8;
    const u16* gV = Vb + (size_t)sr * N_SEQ + ssl * 8;

    f32x4 acc[4] = {};
    float lac0 = 0.f, lac1 = 0.f, lac2 = 0.f, lac3 = 0.f;
    uint2 bcur[4], bnxt[4];

    gload16(gK,              (u16*)&kbuf[0][0][0] + w * 512);
    gload16(gV,              (u16*)&vbuf[0][0][0] + w * 512);
    gload16(gK + 64 * D_DIM, (u16*)&kbuf[1][0][0] + w * 512);
    gload16(gV + 64,         (u16*)&vbuf[1][0][0] + w * 512);
    __builtin_amdgcn_sched_barrier(0);
    #pragma unroll
    for (int fn = 0; fn < 4; ++fn)
        bcur[fn] = *(const uint2*)(Bb + fn * 16 + g * 4);
    __builtin_amdgcn_sched_barrier(0);
    asm volatile("s_waitcnt vmcnt(6)" ::: "memory");
    __builtin_amdgcn_s_barrier();

    for (int kt = 0; kt < NT; ++kt) {
        const int bi = kt % 3;
        if (kt + 1 < NT) {
            #pragma unroll
            for (int fn = 0; fn < 4; ++fn)
                bnxt[fn] = *(const uint2*)(Bb + (kt + 1) * 64 + fn * 16 + g * 4);
        }
        __builtin_amdgcn_sched_barrier(0);
        if (kt + 2 < NT) {
            const int bn = (kt + 2) % 3;
            gload16(gK + (size_t)(kt + 2) * 64 * D_DIM, (u16*)&kbuf[bn][0][0] + w * 512);
            gload16(gV + (kt + 2) * 64,                 (u16*)&vbuf[bn][0][0] + w * 512);
        }
        __builtin_amdgcn_sched_barrier(0);

        f32x4 st[4] = {};
        __builtin_amdgcn_s_setprio(1);
        #pragma unroll
        for (int fn = 0; fn < 4; ++fn) {
            short8 ak0 = *(const short8*)&kbuf[bi][fn * 16 + lr][(g ^ sx) * 8];
            short8 ak1 = *(const short8*)&kbuf[bi][fn * 16 + lr][((4 + g) ^ sx) * 8];
            st[fn] = MFMA16(ak0, aq0, st[fn], 0, 0, 0);
            st[fn] = MFMA16(ak1, aq1, st[fn], 0, 0, 0);
        }
        __builtin_amdgcn_s_setprio(0);

        float sv[16];
        #pragma unroll
        for (int fn = 0; fn < 4; ++fn) {
            sv[fn * 4 + 0] = fmaf(st[fn][0], SC, b2f_lo(bcur[fn].x));
            sv[fn * 4 + 1] = fmaf(st[fn][1], SC, b2f_hi(bcur[fn].x));
            sv[fn * 4 + 2] = fmaf(st[fn][2], SC, b2f_lo(bcur[fn].y));
            sv[fn * 4 + 3] = fmaf(st[fn][3], SC, b2f_hi(bcur[fn].y));
        }
        #pragma unroll
        for (int j = 0; j < 4; ++j)  { sv[j]  = fexp2(sv[j]);  lac0 += sv[j]; }
        #pragma unroll
        for (int j = 4; j < 8; ++j)  { sv[j]  = fexp2(sv[j]);  lac1 += sv[j]; }
        #pragma unroll
        for (int j = 8; j < 12; ++j) { sv[j]  = fexp2(sv[j]);  lac2 += sv[j]; }
        #pragma unroll
        for (int j = 12; j < 16; ++j){ sv[j]  = fexp2(sv[j]);  lac3 += sv[j]; }

        #pragma unroll
        for (int fn = 0; fn < 4; ++fn) {
            union { float f; u32 u; } p0, p1, p2, p3;
            p0.f = sv[fn * 4 + 0]; p1.f = sv[fn * 4 + 1];
            p2.f = sv[fn * 4 + 2]; p3.f = sv[fn * 4 + 3];
            uint2 pk;
            pk.x = (p1.u & 0xFFFF0000u) | (p0.u >> 16);
            pk.y = (p3.u & 0xFFFF0000u) | (p2.u >> 16);
            int slot = fn * 2 + (g >> 1);
            *(uint2*)&pbuf[w][lr][(slot ^ sx) * 8 + (g & 1) * 4] = pk;
        }
        asm volatile("s_waitcnt lgkmcnt(0)" ::: "memory");
        __builtin_amdgcn_sched_barrier(0);

        short8 bp0 = *(const short8*)&pbuf[w][lr][(g ^ sx) * 8];
        short8 bp1 = *(const short8*)&pbuf[w][lr][((4 + g) ^ sx) * 8];

        __builtin_amdgcn_s_setprio(1);
        #pragma unroll
        for (int df = 0; df < 4; ++df) {
            short8 av0 = *(const short8*)&vbuf[bi][df * 16 + lr][(g ^ sx) * 8];
            short8 av1 = *(const short8*)&vbuf[bi][df * 16 + lr][((4 + g) ^ sx) * 8];
            acc[df] = MFMA16(av0, bp0, acc[df], 0, 0, 0);
            acc[df] = MFMA16(av1, bp1, acc[df], 0, 0, 0);
        }
        __builtin_amdgcn_s_setprio(0);

        #pragma unroll
        for (int fn = 0; fn < 4; ++fn) bcur[fn] = bnxt[fn];

        if (kt + 1 < NT) {
            if (kt + 2 < NT) asm volatile("s_waitcnt vmcnt(6)" ::: "memory");
            else             asm volatile("s_waitcnt vmcnt(4)" ::: "memory");
            __builtin_amdgcn_s_barrier();
        }
    }

    float l_run = (lac0 + lac1) + (lac2 + lac3);
    l_run += __shfl_xor(l_run, 16);
    l_run += __shfl_xor(l_run, 32);
    float rl;
    asm("v_rcp_f32 %0, %1" : "=v"(rl) : "v"(l_run));
    rl = rl * (2.f - l_run * rl);
    u16* ob = attn_out + ((size_t)(b * N_SEQ + q)) * C_DIM + h * D_DIM + g * 4;
    #pragma unroll
    for (int df = 0; df < 4; ++df) {
        u32 w0 = ((u32)f2b(acc[df][1] * rl) << 16) | f2b(acc[df][0] * rl);
        u32 w1 = ((u32)f2b(acc[df][3] * rl) << 16) | f2b(acc[df][2] * rl);
        uint2 pk; pk.x = w0; pk.y = w1;
        *(uint2*)(ob + df * 16) = pk;
    }
}

// ---------------------------------------------------------------------------
// LayerNorm over h (residual already fused). One WAVE per row (4 rows/block),
// pure shuffle reduction — no LDS, no __syncthreads. 8 floats/lane.
// ---------------------------------------------------------------------------
__global__ __launch_bounds__(256) void k_ln(const float* __restrict__ hbuf,
                                            const float* __restrict__ gamma,
                                            const float* __restrict__ beta,
                                            float* __restrict__ out)
{
    const int t = threadIdx.x;
    const int w = t >> 6, l = t & 63;
    const int r = blockIdx.x * 4 + w;
    const size_t base = (size_t)r * C_DIM + l * 8;
    float4 h0 = *(const float4*)(hbuf + base);
    float4 h1 = *(const float4*)(hbuf + base + 4);
    float s  = (h0.x + h0.y) + (h0.z + h0.w) + (h1.x + h1.y) + (h1.z + h1.w);
    float sq = (h0.x * h0.x + h0.y * h0.y) + (h0.z * h0.z + h0.w * h0.w)
             + (h1.x * h1.x + h1.y * h1.y) + (h1.z * h1.z + h1.w * h1.w);
    #pragma unroll
    for (int m = 1; m < 64; m <<= 1) {
        s  += __shfl_xor(s, m);
        sq += __shfl_xor(sq, m);
    }
    float mu = s * (1.f / C_DIM);
    float var = sq * (1.f / C_DIM) - mu * mu;
    float inv = rsqrtf(var + 1e-5f);
    float4 g0 = *(const float4*)(gamma + l * 8);
    float4 g1 = *(const float4*)(gamma + l * 8 + 4);
    float4 b0 = *(const float4*)(beta + l * 8);
    float4 b1 = *(const float4*)(beta + l * 8 + 4);
    float4 o0, o1;
    o0.x = (h0.x - mu) * inv * g0.x + b0.x;
    o0.y = (h0.y - mu) * inv * g0.y + b0.y;
    o0.z = (h0.z - mu) * inv * g0.z + b0.z;
    o0.w = (h0.w - mu) * inv * g0.w + b0.w;
    o1.x = (h1.x - mu) * inv * g1.x + b1.x;
    o1.y = (h1.y - mu) * inv * g1.y + b1.y;
    o1.z = (h1.z - mu) * inv * g1.z + b1.z;
    o1.w = (h1.w - mu) * inv * g1.w + b1.w;
    *(float4*)(out + base) = o0;
    *(float4*)(out + base + 4) = o1;
}

// ---------------------------------------------------------------------------
extern "C" void kernel_launch(void* const* d_in, const int* in_sizes, int n_in,
                              void* d_out, int out_size, void* d_ws, size_t ws_size,
                              hipStream_t stream)
{
    const float* qc    = (const float*)d_in[0];
    const float* qpos  = (const float*)d_in[1];
    const float* Wq    = (const float*)d_in[2];
    const float* bq    = (const float*)d_in[3];
    const float* Wk    = (const float*)d_in[4];
    const float* bk    = (const float*)d_in[5];
    const float* Wv    = (const float*)d_in[6];
    const float* bv    = (const float*)d_in[7];
    const float* Wo    = (const float*)d_in[8];
    const float* bo    = (const float*)d_in[9];
    const float* gamma = (const float*)d_in[10];
    const float* beta  = (const float*)d_in[11];
    float* out = (float*)d_out;

    char* ws = (char*)d_ws;
    const size_t MB = 1024 * 1024;
    u16*   bias_ws = (u16*)(ws);                   // 32 MB bf16 [4][2048][2048]
    u16*   xb_ws   = (u16*)(ws + 32 * MB);         //  8 MB bf16 X
    u16*   wb_ws   = (u16*)(ws + 40 * MB);         //  2 MB bf16 [2048][512]
    float* bqkv_ws = (float*)(ws + 42 * MB);       //  8 KB fp32 bq|bk|bv|bo
    u16*   q_ws    = (u16*)(ws + 43 * MB);         //  8 MB bf16 Q [B][H][N][D]
    u16*   k_ws    = (u16*)(ws + 51 * MB);         //  8 MB bf16 K [B][H][N][D]
    u16*   v_ws    = (u16*)(ws + 59 * MB);         //  8 MB bf16 V [B][H][D][N]
    u16*   a_ws    = (u16*)(ws + 75 * MB);         //  8 MB bf16 attn out
    float* p_ws    = (float*)(ws + 43 * MB);       // 16 MB fp32 h (aliases q/k: dead)

    k_prep<<<dim3(10760), 256, 0, stream>>>(qc, Wq, Wk, Wv, Wo, bq, bk, bv, bo,
                                            qpos, xb_ws, wb_ws, bqkv_ws, bias_ws);
    k_gemm<<<dim3(M_TOT / 128, 12), 256, 0, stream>>>(xb_ws, wb_ws, bqkv_ws, nullptr,
                                                      q_ws, k_ws, v_ws, nullptr, -1);
    k_flash<<<dim3(16, 32), 512, 0, stream>>>(q_ws, k_ws, v_ws, bias_ws, a_ws);
    k_gemm<<<dim3(M_TOT / 128, 4), 256, 0, stream>>>(a_ws, wb_ws + 1536 * 512,
                                                     bqkv_ws + 1536, qc,
                                                     nullptr, nullptr, nullptr, p_ws, 3);
    k_ln<<<dim3(M_TOT / 4), 256, 0, stream>>>(p_ws, gamma, beta, out);
}